// Round 13
// baseline (327.545 us; speedup 1.0000x reference)
//
#include <hip/hip_runtime.h>

// Problem constants
#define B_ 32
#define N_ 256
#define D_ 512
#define H_ 8
#define E_ 1024
#define HD_ 64

using u16 = unsigned short;
typedef short bf8_t __attribute__((ext_vector_type(8)));
typedef float f4_t __attribute__((ext_vector_type(4)));

__device__ __forceinline__ u16 f2bf(float f) {
  union { float f; unsigned u; } x; x.f = f;
  unsigned r = x.u + 0x7fffu + ((x.u >> 16) & 1u);
  return (u16)(r >> 16);
}
__device__ __forceinline__ float bf2f(u16 x) {
  union { unsigned u; float f; } y; y.u = ((unsigned)x) << 16; return y.f;
}
__device__ __forceinline__ f4_t mfma16(bf8_t a, bf8_t b, f4_t c) {
  return __builtin_amdgcn_mfma_f32_16x16x32_bf16(a, b, c, 0, 0, 0);
}
__device__ __forceinline__ void gload_lds16(const u16* g, u16* s) {
  __builtin_amdgcn_global_load_lds((const __attribute__((address_space(1))) void*)g,
                                   (__attribute__((address_space(3))) void*)s, 16, 0, 0);
}

// Wave-per-row LN of a 512-wide f32 row -> bf16. Lane l owns elems [8l, 8l+8):
// 2x float4 loads, 6-round shfl_xor reduce, one 16B bf8 store. No LDS, no barriers. (G13)
__device__ __forceinline__ void ln_row_wave(const float* __restrict__ xr, int lane,
                                            const float* __restrict__ g,
                                            const float* __restrict__ bta,
                                            u16* __restrict__ outp) {
  const float4 a0 = *(const float4*)(xr + lane * 8);
  const float4 a1 = *(const float4*)(xr + lane * 8 + 4);
  float s  = a0.x + a0.y + a0.z + a0.w + a1.x + a1.y + a1.z + a1.w;
  float ss = a0.x * a0.x + a0.y * a0.y + a0.z * a0.z + a0.w * a0.w +
             a1.x * a1.x + a1.y * a1.y + a1.z * a1.z + a1.w * a1.w;
  #pragma unroll
  for (int m = 1; m < 64; m <<= 1) { s += __shfl_xor(s, m, 64); ss += __shfl_xor(ss, m, 64); }
  const float mean = s * (1.f / D_);
  const float rs = rsqrtf(ss * (1.f / D_) - mean * mean + 1e-5f);
  const float4 g0 = *(const float4*)(g + lane * 8);
  const float4 g1 = *(const float4*)(g + lane * 8 + 4);
  const float4 b0 = *(const float4*)(bta + lane * 8);
  const float4 b1 = *(const float4*)(bta + lane * 8 + 4);
  bf8_t res;
  res[0] = (short)f2bf((a0.x - mean) * rs * g0.x + b0.x);
  res[1] = (short)f2bf((a0.y - mean) * rs * g0.y + b0.y);
  res[2] = (short)f2bf((a0.z - mean) * rs * g0.z + b0.z);
  res[3] = (short)f2bf((a0.w - mean) * rs * g0.w + b0.w);
  res[4] = (short)f2bf((a1.x - mean) * rs * g1.x + b1.x);
  res[5] = (short)f2bf((a1.y - mean) * rs * g1.y + b1.y);
  res[6] = (short)f2bf((a1.z - mean) * rs * g1.z + b1.z);
  res[7] = (short)f2bf((a1.w - mean) * rs * g1.w + b1.w);
  *(bf8_t*)(outp + lane * 8) = res;
}

// ---------------- prep: cvt + ln1 + scatter + edge_gemm(inline geo-LN), one launch --------
// block ranges: [0,1536) cvt (8 f32/thread); [1536,2560) LN(x) 8 rows/block;
//               [2560,2688) scatter; [2688,3200) edge-bias GEMM (padded LDS rows).
#define WEBP 264
#define WGEOP 72
__global__ __launch_bounds__(256) void prep_kernel(
    // cvt
    const float* __restrict__ wq, const float* __restrict__ wk,
    const float* __restrict__ wv, const float* __restrict__ wo,
    const float* __restrict__ w1, const float* __restrict__ w2,
    u16* __restrict__ dq, u16* __restrict__ dk, u16* __restrict__ dv,
    u16* __restrict__ dox, u16* __restrict__ d1, u16* __restrict__ d2,
    // ln1
    const float* __restrict__ x, const float* __restrict__ ng,
    const float* __restrict__ nb, u16* __restrict__ xn,
    // scatter
    const int* __restrict__ edges, const float* __restrict__ rmask,
    int* __restrict__ win,
    // edge
    const float* __restrict__ remb, const float* __restrict__ rgeo,
    const float* __restrict__ Web, const float* __restrict__ beb,
    const float* __restrict__ glng, const float* __restrict__ glnb,
    const float* __restrict__ Wgeo, const float* __restrict__ bgeo,
    float* __restrict__ tb) {
  __shared__ u16 sWeb[16 * WEBP];
  __shared__ u16 sWgeo[16 * WGEOP];
  __shared__ float sLgb[128];
  const int t = threadIdx.x;
  const int blk0 = blockIdx.x;

  if (blk0 < 1536) {
    // ---- weight f32 -> bf16: 8 floats/thread (2x float4 -> one 16B store) ----
    int blk = blk0;
    const float* src; u16* dst;
    if (blk < 128)        { src = wq; dst = dq; }
    else if (blk < 256)   { src = wk; dst = dk; blk -= 128; }
    else if (blk < 384)   { src = wv; dst = dv; blk -= 256; }
    else if (blk < 512)   { src = wo; dst = dox; blk -= 384; }
    else if (blk < 1024)  { src = w1; dst = d1; blk -= 512; }
    else                  { src = w2; dst = d2; blk -= 1024; }
    const int i = (blk * 256 + t) * 8;
    const float4 v0 = *(const float4*)(src + i);
    const float4 v1 = *(const float4*)(src + i + 4);
    bf8_t o;
    o[0] = (short)f2bf(v0.x); o[1] = (short)f2bf(v0.y);
    o[2] = (short)f2bf(v0.z); o[3] = (short)f2bf(v0.w);
    o[4] = (short)f2bf(v1.x); o[5] = (short)f2bf(v1.y);
    o[6] = (short)f2bf(v1.z); o[7] = (short)f2bf(v1.w);
    *(bf8_t*)(dst + i) = o;
  } else if (blk0 < 2560) {
    // ---- LN(x): 8 rows per block, one wave per row x2 ----
    const int base = (blk0 - 1536) * 8 + (t >> 6) * 2;
    const int lane = t & 63;
    #pragma unroll
    for (int r = 0; r < 2; ++r) {
      const int row = base + r;
      ln_row_wave(x + (size_t)row * D_, lane, ng, nb, xn + (size_t)row * D_);
    }
  } else if (blk0 < 2688) {
    // ---- winner scatter (np last-write-wins) ----
    const int idx = (blk0 - 2560) * 256 + t;  // b*E + e
    if (rmask[idx] != 0.f) {
      const int b = idx >> 10, e = idx & (E_ - 1);
      int s = edges[2 * idx], d = edges[2 * idx + 1];
      s = min(max(s, 0), N_ - 1);
      d = min(max(d, 0), N_ - 1);
      int* wb = win + (size_t)b * N_ * N_;
      atomicMax(&wb[s * N_ + d], e);        // pass 1: priority e
      atomicMax(&wb[d * N_ + s], E_ + e);   // pass 2: priority E+e
    }
  } else {
    // ---- edge bias GEMM with inline geo LN ----
    const int eblk = blk0 - 2688;
    for (int i = t; i < 2048; i += 256) {
      const int r = i >> 8, c = i & 255;
      sWeb[r * WEBP + c] = f2bf(Web[i]);
      sWeb[(8 + r) * WEBP + c] = 0;
    }
    for (int i = t; i < 512; i += 256) {
      const int r = i >> 6, c = i & 63;
      sWgeo[r * WGEOP + c] = f2bf(Wgeo[i]);
      sWgeo[(8 + r) * WGEOP + c] = 0;
    }
    if (t < 64) { sLgb[t] = glng[t]; sLgb[64 + t] = glnb[t]; }
    __syncthreads();
    const int wave = t >> 6, lane = t & 63;
    const int am = lane & 15, quad = lane >> 4;
    const int e0 = eblk * 64 + wave * 16;

    f4_t acc = f4_t{0.f, 0.f, 0.f, 0.f};
    const float* ar = remb + (size_t)(e0 + am) * 256 + quad * 8;
    #pragma unroll
    for (int kt = 0; kt < 256; kt += 32) {
      const float4 p0 = *(const float4*)(ar + kt);
      const float4 p1 = *(const float4*)(ar + kt + 4);
      bf8_t a;
      a[0] = (short)f2bf(p0.x); a[1] = (short)f2bf(p0.y);
      a[2] = (short)f2bf(p0.z); a[3] = (short)f2bf(p0.w);
      a[4] = (short)f2bf(p1.x); a[5] = (short)f2bf(p1.y);
      a[6] = (short)f2bf(p1.z); a[7] = (short)f2bf(p1.w);
      const bf8_t bv = *(const bf8_t*)&sWeb[am * WEBP + kt + quad * 8];
      acc = mfma16(a, bv, acc);
    }
    // geo: row (e0+am), lane holds elems quad*8..+7 and 32+quad*8..+7
    const float* gr = rgeo + (size_t)(e0 + am) * 64;
    float v[16];
    {
      const float4 p0 = *(const float4*)(gr + quad * 8);
      const float4 p1 = *(const float4*)(gr + quad * 8 + 4);
      const float4 p2 = *(const float4*)(gr + 32 + quad * 8);
      const float4 p3 = *(const float4*)(gr + 32 + quad * 8 + 4);
      v[0] = p0.x; v[1] = p0.y; v[2] = p0.z; v[3] = p0.w;
      v[4] = p1.x; v[5] = p1.y; v[6] = p1.z; v[7] = p1.w;
      v[8] = p2.x; v[9] = p2.y; v[10] = p2.z; v[11] = p2.w;
      v[12] = p3.x; v[13] = p3.y; v[14] = p3.z; v[15] = p3.w;
    }
    float s = 0.f, ss = 0.f;
    #pragma unroll
    for (int j = 0; j < 16; ++j) { s += v[j]; ss += v[j] * v[j]; }
    s += __shfl_xor(s, 16, 64);  ss += __shfl_xor(ss, 16, 64);
    s += __shfl_xor(s, 32, 64);  ss += __shfl_xor(ss, 32, 64);
    const float mean = s * (1.f / 64.f);
    const float rs = rsqrtf(ss * (1.f / 64.f) - mean * mean + 1e-5f);
    bf8_t a2, a3;
    #pragma unroll
    for (int j = 0; j < 8; ++j) {
      a2[j] = (short)f2bf((v[j] - mean) * rs * sLgb[quad * 8 + j] + sLgb[64 + quad * 8 + j]);
      a3[j] = (short)f2bf((v[8 + j] - mean) * rs * sLgb[32 + quad * 8 + j] +
                          sLgb[96 + quad * 8 + j]);
    }
    acc = mfma16(a2, *(const bf8_t*)&sWgeo[am * WGEOP + quad * 8], acc);
    acc = mfma16(a3, *(const bf8_t*)&sWgeo[am * WGEOP + 32 + quad * 8], acc);
    if (am < 8) {
      const float bias_v = beb[am] + bgeo[am];
      #pragma unroll
      for (int r = 0; r < 4; ++r) {
        const int eg = e0 + quad * 4 + r;
        tb[(size_t)((eg >> 10) * H_ + am) * E_ + (eg & (E_ - 1))] = acc[r] + bias_v;
      }
    }
  }
}

// ---------------- LayerNorm: 8 rows/block, wave per row x2 (f32 in -> bf16 out) --------
__global__ __launch_bounds__(256) void ln_kernel(const float* __restrict__ x,
                                                 const float* __restrict__ g,
                                                 const float* __restrict__ bta,
                                                 u16* __restrict__ out) {
  const int base = blockIdx.x * 8 + (threadIdx.x >> 6) * 2;
  const int lane = threadIdx.x & 63;
  #pragma unroll
  for (int r = 0; r < 2; ++r) {
    const int row = base + r;
    ln_row_wave(x + (size_t)row * D_, lane, g, bta, out + (size_t)row * D_);
  }
}

// ---------------- sparse attention: one wave per (b,row), all heads ----------------
__global__ __launch_bounds__(256) void attn_kernel(
    const u16* __restrict__ q, const u16* __restrict__ k, const u16* __restrict__ v,
    const float* __restrict__ tb, const int* __restrict__ win,
    const float* __restrict__ nm, u16* __restrict__ out) {
  const int t = threadIdx.x;
  const int wave = t >> 6, lane = t & 63;
  const int g = blockIdx.x * 4 + wave;      // b*N + row
  const int b = g >> 8, row = g & (N_ - 1);
  u16* op = out + (size_t)g * D_ + lane * 8;
  const float nmr = nm[g];
  if (nmr == 0.f) {
    bf8_t z = 0;
    *(bf8_t*)op = z;
    return;
  }
  float qf[8];
  {
    const bf8_t qv = *(const bf8_t*)(q + (size_t)g * D_ + lane * 8);
    #pragma unroll
    for (int j = 0; j < 8; ++j) qf[j] = bf2f((u16)qv[j]);
  }
  int4 w4 = *(const int4*)(win + (size_t)g * N_ + lane * 4);
  if (lane == (row >> 2)) {
    const int sl = row & 3;
    if (sl == 0)      { if (w4.x == -1) w4.x = 0x7FFFFFFF; }
    else if (sl == 1) { if (w4.y == -1) w4.y = 0x7FFFFFFF; }
    else if (sl == 2) { if (w4.z == -1) w4.z = 0x7FFFFFFF; }
    else              { if (w4.w == -1) w4.w = 0x7FFFFFFF; }
  }
  const float* tbh = tb + (size_t)(b * H_ + (lane >> 3)) * E_;
  const float* nmb = nm + b * N_;
  const u16* kb = k + (size_t)b * N_ * D_;
  const u16* vb = v + (size_t)b * N_ * D_;
  float m = -3.402823466e38f, sum = 0.f;
  float o[8];
  #pragma unroll
  for (int j = 0; j < 8; ++j) o[j] = 0.f;
  #pragma unroll
  for (int c = 0; c < 4; ++c) {
    const int wc = (c == 0) ? w4.x : (c == 1) ? w4.y : (c == 2) ? w4.z : w4.w;
    unsigned long long mk = __ballot(wc != -1);
    while (mk) {
      const int jl = __builtin_ctzll(mk);
      mk &= mk - 1;
      const int col = jl * 4 + c;
      const int wv = __shfl(wc, jl, 64);
      const float nmc = nmb[col];
      if (nmc == 0.f) continue;
      const bf8_t kv = *(const bf8_t*)(kb + (size_t)col * D_ + lane * 8);
      float d = 0.f;
      #pragma unroll
      for (int j = 0; j < 8; ++j) d += qf[j] * bf2f((u16)kv[j]);
      d += __shfl_xor(d, 1, 64);
      d += __shfl_xor(d, 2, 64);
      d += __shfl_xor(d, 4, 64);
      float s = d * 0.125f;
      if ((unsigned)wv < 2048u) s += tbh[wv & (E_ - 1)];
      const bf8_t vv = *(const bf8_t*)(vb + (size_t)col * D_ + lane * 8);
      if (s > m) {
        const float sc = __expf(m - s);
        sum *= sc;
        #pragma unroll
        for (int j = 0; j < 8; ++j) o[j] *= sc;
        m = s;
      }
      const float p = __expf(s - m);
      sum += p;
      #pragma unroll
      for (int j = 0; j < 8; ++j) o[j] += p * bf2f((u16)vv[j]);
    }
  }
  const float rinv = 1.f / sum;
  bf8_t res;
  #pragma unroll
  for (int j = 0; j < 8; ++j) res[j] = (short)f2bf(o[j] * rinv);
  *(bf8_t*)op = res;
}

// ---------------- GEMM: 64x64 tiles, 3-deep circular LDS pipeline, counted vmcnt -------
// Untried cell of the design space: small tiles (16KB/buf x3 = 48KB -> 3 blocks/CU, same
// residency as the 285us best) + 3-deep prefetch (stage t+2 issued before computing t;
// vmcnt(8) waits only for tile t's 4 loads/thread, t+1/t+2's 8 stay in flight across TWO
// compute+barrier iterations -> ~900cy staging latency fully hidden). Counted-vmcnt +
// raw-barrier idiom correctness-proven in round 6. Swapped MFMA + vector epilogue kept.
template <int MODE, int BN>
__global__ __launch_bounds__(256, 3) void gemm_k(
    const u16* __restrict__ A,
    const u16* __restrict__ W0, const u16* __restrict__ W1, const u16* __restrict__ W2,
    const float* __restrict__ b0, const float* __restrict__ b1, const float* __restrict__ b2,
    void* d0, void* d1, void* d2,
    const void* res, const float* __restrict__ nmask, int K) {
  constexpr int MJ = BN / 32;   // = 2
  constexpr int CB = BN / 32;   // = 2
  __shared__ u16 As[3][64 * 64];
  __shared__ u16 Bs[3][BN * 64];
  const int tid = threadIdx.x;
  const int wave = tid >> 6, lane = tid & 63;
  const int am = lane & 15, quad = lane >> 4;
  const int m0 = blockIdx.x * 64;
  int n0, proj = 0;
  const u16* W;
  const float* bias;
  if constexpr (MODE == 0) {
    constexpr int NPB = 512 / BN;  // n-blocks per projection
    proj = blockIdx.y / NPB;
    n0 = (blockIdx.y % NPB) * BN;
    W = proj == 0 ? W0 : (proj == 1 ? W1 : W2);
    bias = proj == 0 ? b0 : (proj == 1 ? b1 : b2);
  } else {
    n0 = blockIdx.y * BN;
    W = W0;
    bias = b0;
  }
  const int wm = (wave >> 1) * 32;
  const int wn = (wave & 1) * (BN / 2);

  f4_t acc[2][MJ];
  #pragma unroll
  for (int i = 0; i < 2; ++i)
    #pragma unroll
    for (int j = 0; j < MJ; ++j) acc[i][j] = f4_t{0.f, 0.f, 0.f, 0.f};

  int arow[2], aq[2], brow[CB], bq[CB];
  #pragma unroll
  for (int c = 0; c < 2; ++c) {
    const int g = (wave * 2 + c) * 64 + lane;
    arow[c] = g >> 3;
    aq[c] = (g & 7) ^ (arow[c] & 7);
  }
  #pragma unroll
  for (int c = 0; c < CB; ++c) {
    const int g = (wave * CB + c) * 64 + lane;
    brow[c] = g >> 3;
    bq[c] = (g & 7) ^ (brow[c] & 7);
  }

  const int nsteps = K >> 6;
  // stage K-tile `s` into buffer `buf` (4 gload_lds16 per thread: 2 A + 2 B)
  auto STAGE = [&](int s, int buf) {
    const int kt = s * 64;
    #pragma unroll
    for (int c = 0; c < 2; ++c)
      gload_lds16(A + (size_t)(m0 + arow[c]) * K + kt + aq[c] * 8,
                  &As[buf][(wave * 2 + c) * 512]);
    #pragma unroll
    for (int c = 0; c < CB; ++c)
      gload_lds16(W + (size_t)(n0 + brow[c]) * K + kt + bq[c] * 8,
                  &Bs[buf][(wave * CB + c) * 512]);
  };

  // prologue: tiles 0 and 1 in flight
  STAGE(0, 0);
  if (nsteps > 1) STAGE(1, 1);

  int cur = 0;                       // buffer holding tile t
  for (int t = 0; t < nsteps; ++t) {
    int nxt2 = cur + 2; if (nxt2 >= 3) nxt2 -= 3;   // buffer for tile t+2
    if (t + 2 < nsteps) {
      STAGE(t + 2, nxt2);
      // outstanding: t (4), t+1 (4), t+2 (4). Wait until only 8 remain -> tile t landed.
      asm volatile("s_waitcnt vmcnt(8)" ::: "memory");
    } else if (t + 1 < nsteps) {
      // outstanding: t (4), t+1 (4). Wait until 4 remain -> tile t landed.
      asm volatile("s_waitcnt vmcnt(4)" ::: "memory");
    } else {
      asm volatile("s_waitcnt vmcnt(0)" ::: "memory");
    }
    asm volatile("s_barrier" ::: "memory");  // all waves' tile-t DMA landed
    #pragma unroll
    for (int kc = 0; kc < 2; ++kc) {
      bf8_t af[2], bfv[MJ];
      #pragma unroll
      for (int i = 0; i < 2; ++i) {
        const int r = wm + i * 16 + am;
        af[i] = *(const bf8_t*)&As[cur][r * 64 + (((kc * 4 + quad) ^ (r & 7)) * 8)];
      }
      #pragma unroll
      for (int j = 0; j < MJ; ++j) {
        const int r = wn + j * 16 + am;
        bfv[j] = *(const bf8_t*)&Bs[cur][r * 64 + (((kc * 4 + quad) ^ (r & 7)) * 8)];
      }
      #pragma unroll
      for (int i = 0; i < 2; ++i)
        #pragma unroll
        for (int j = 0; j < MJ; ++j)
          acc[i][j] = mfma16(bfv[j], af[i], acc[i][j]);  // swapped: D rows<-N, cols<-M
    }
    asm volatile("s_barrier" ::: "memory");  // reads of cur done before stage(t+3) overwrite
    ++cur; if (cur >= 3) cur = 0;
  }

  // Epilogue: lane holds rows (wm+i*16+am), cols (wn+j*16+quad*4 .. +3) -> vector stores
  const int row0 = m0 + wm + am;
  const int col0 = n0 + wn + quad * 4;
  #pragma unroll
  for (int j = 0; j < MJ; ++j) {
    const int col = col0 + j * 16;
    const float4 bv4 = *(const float4*)(bias + col);
    #pragma unroll
    for (int i = 0; i < 2; ++i) {
      const int row = row0 + i * 16;
      float v0 = acc[i][j][0] + bv4.x;
      float v1 = acc[i][j][1] + bv4.y;
      float v2 = acc[i][j][2] + bv4.z;
      float v3 = acc[i][j][3] + bv4.w;
      if constexpr (MODE == 0) {
        u16* dst = (u16*)(proj == 0 ? d0 : (proj == 1 ? d1 : d2));
        ushort4 o; o.x = f2bf(v0); o.y = f2bf(v1); o.z = f2bf(v2); o.w = f2bf(v3);
        *(ushort4*)(dst + (size_t)row * D_ + col) = o;
      } else if constexpr (MODE == 2) {
        const float4 rr = *(const float4*)((const float*)res + (size_t)row * D_ + col);
        float4 o; o.x = v0 + rr.x; o.y = v1 + rr.y; o.z = v2 + rr.z; o.w = v3 + rr.w;
        *(float4*)((float*)d0 + (size_t)row * D_ + col) = o;
      } else if constexpr (MODE == 3) {
        v0 = v0 / (1.f + __expf(-v0));
        v1 = v1 / (1.f + __expf(-v1));
        v2 = v2 / (1.f + __expf(-v2));
        v3 = v3 / (1.f + __expf(-v3));
        ushort4 o; o.x = f2bf(v0); o.y = f2bf(v1); o.z = f2bf(v2); o.w = f2bf(v3);
        *(ushort4*)((u16*)d0 + (size_t)row * 2048 + col) = o;
      } else {
        const float4 rr = *(const float4*)((const float*)res + (size_t)row * D_ + col);
        const float nmv = nmask[row];
        float4 o;
        o.x = (v0 + rr.x) * nmv; o.y = (v1 + rr.y) * nmv;
        o.z = (v2 + rr.z) * nmv; o.w = (v3 + rr.w) * nmv;
        *(float4*)((float*)d0 + (size_t)row * D_ + col) = o;
      }
    }
  }
}

extern "C" void kernel_launch(void* const* d_in, const int* in_sizes, int n_in,
                              void* d_out, int out_size, void* d_ws, size_t ws_size,
                              hipStream_t stream) {
  const float* x     = (const float*)d_in[0];
  const float* nm    = (const float*)d_in[1];
  const int*   edges = (const int*)d_in[2];
  const float* rmask = (const float*)d_in[3];
  const float* remb  = (const float*)d_in[4];
  const float* rgeo  = (const float*)d_in[5];
  const float* Wq = (const float*)d_in[6];  const float* bq = (const float*)d_in[7];
  const float* Wk = (const float*)d_in[8];  const float* bk = (const float*)d_in[9];
  const float* Wv = (const float*)d_in[10]; const float* bv = (const float*)d_in[11];
  const float* Web = (const float*)d_in[12]; const float* beb = (const float*)d_in[13];
  const float* glng = (const float*)d_in[14]; const float* glnb = (const float*)d_in[15];
  const float* Wgeo = (const float*)d_in[16]; const float* bgeo = (const float*)d_in[17];
  const float* Wout = (const float*)d_in[18]; const float* bout = (const float*)d_in[19];
  const float* ng = (const float*)d_in[20]; const float* nb = (const float*)d_in[21];
  const float* fg = (const float*)d_in[22]; const float* fb = (const float*)d_in[23];
  const float* Wff1 = (const float*)d_in[24]; const float* bff1 = (const float*)d_in[25];
  const float* Wff2 = (const float*)d_in[26]; const float* bff2 = (const float*)d_in[27];

  char* ws = (char*)d_ws;
  u16*   xn      = (u16*)(ws + 0);
  u16*   qb      = (u16*)(ws + 8388608);
  u16*   kb      = (u16*)(ws + 16777216);
  u16*   vb      = (u16*)(ws + 25165824);
  u16*   h1      = (u16*)(ws + 0);          // overlays dead xn/qb/kb/vb in FF
  int*   win     = (int*)(ws + 33554432);
  u16*   x2n     = (u16*)(ws + 33554432);   // overlays dead win
  float* tb      = (float*)(ws + 41943040);
  u16* Wq16   = (u16*)(ws + 42991616);
  u16* Wk16   = (u16*)(ws + 43515904);
  u16* Wv16   = (u16*)(ws + 44040192);
  u16* Wout16 = (u16*)(ws + 44564480);
  u16* Wff116 = (u16*)(ws + 45088768);
  u16* Wff216 = (u16*)(ws + 47185920);
  u16*   attnout = xn;
  float* out     = (float*)d_out;

  // 0. win init, then fused prep (cvt + ln1 + scatter + edge-bias GEMM) in ONE launch
  hipMemsetAsync(win, 0xFF, (size_t)B_ * N_ * N_ * sizeof(int), stream);
  prep_kernel<<<3200, 256, 0, stream>>>(
      Wq, Wk, Wv, Wout, Wff1, Wff2, Wq16, Wk16, Wv16, Wout16, Wff116, Wff216,
      x, ng, nb, xn,
      edges, rmask, win,
      remb, rgeo, Web, beb, glng, glnb, Wgeo, bgeo, tb);
  // 1. fused QKV projections; 64x64 tiles -> grid (128, 24) = 3072 blocks
  gemm_k<0, 64><<<dim3(128, 24), 256, 0, stream>>>(xn, Wq16, Wk16, Wv16, bq, bk, bv,
                                                   (void*)qb, (void*)kb, (void*)vb,
                                                   nullptr, nullptr, D_);
  // 2. sparse attention -> attnout (bf16); one wave per (b,row)
  attn_kernel<<<dim3(B_ * N_ / 4), 256, 0, stream>>>(qb, kb, vb, tb, win, nm, attnout);
  // 3. x2 = x + attnout @ Wout^T + bout  -> d_out (f32); grid (128, 8)
  gemm_k<2, 64><<<dim3(128, 8), 256, 0, stream>>>(attnout, Wout16, nullptr, nullptr,
                                                  bout, nullptr, nullptr,
                                                  (void*)out, nullptr, nullptr,
                                                  (const void*)x, nullptr, D_);
  // 4. x2n = LN(x2); 8 rows/block wave-per-row
  ln_kernel<<<B_ * N_ / 8, 256, 0, stream>>>(out, fg, fb, x2n);
  // 5. h1 = silu(x2n @ Wff1^T + bff1); grid (128, 32)
  gemm_k<3, 64><<<dim3(128, 32), 256, 0, stream>>>(x2n, Wff116, nullptr, nullptr,
                                                   bff1, nullptr, nullptr,
                                                   (void*)h1, nullptr, nullptr, nullptr, nullptr, D_);
  // 6. out = (x2 + h1 @ Wff2^T + bff2) * node_mask; K=2048 -> 32-step 3-deep pipeline
  gemm_k<4, 64><<<dim3(128, 8), 256, 0, stream>>>(h1, Wff216, nullptr, nullptr,
                                                  bff2, nullptr, nullptr,
                                                  (void*)out, nullptr, nullptr,
                                                  (const void*)out, nm, 2048);
}

// Round 14
// 283.333 us; speedup vs baseline: 1.1560x; 1.1560x over previous
//
#include <hip/hip_runtime.h>

// Problem constants
#define B_ 32
#define N_ 256
#define D_ 512
#define H_ 8
#define E_ 1024
#define HD_ 64

using u16 = unsigned short;
typedef short bf8_t __attribute__((ext_vector_type(8)));
typedef float f4_t __attribute__((ext_vector_type(4)));

__device__ __forceinline__ u16 f2bf(float f) {
  union { float f; unsigned u; } x; x.f = f;
  unsigned r = x.u + 0x7fffu + ((x.u >> 16) & 1u);
  return (u16)(r >> 16);
}
__device__ __forceinline__ float bf2f(u16 x) {
  union { unsigned u; float f; } y; y.u = ((unsigned)x) << 16; return y.f;
}
__device__ __forceinline__ f4_t mfma16(bf8_t a, bf8_t b, f4_t c) {
  return __builtin_amdgcn_mfma_f32_16x16x32_bf16(a, b, c, 0, 0, 0);
}
__device__ __forceinline__ void gload_lds16(const u16* g, u16* s) {
  __builtin_amdgcn_global_load_lds((const __attribute__((address_space(1))) void*)g,
                                   (__attribute__((address_space(3))) void*)s, 16, 0, 0);
}

// Wave-per-row LN of a 512-wide f32 row -> bf16. Lane l owns elems [8l, 8l+8):
// 2x float4 loads, 6-round shfl_xor reduce, one 16B bf8 store. No LDS, no barriers. (G13)
__device__ __forceinline__ void ln_row_wave(const float* __restrict__ xr, int lane,
                                            const float* __restrict__ g,
                                            const float* __restrict__ bta,
                                            u16* __restrict__ outp) {
  const float4 a0 = *(const float4*)(xr + lane * 8);
  const float4 a1 = *(const float4*)(xr + lane * 8 + 4);
  float s  = a0.x + a0.y + a0.z + a0.w + a1.x + a1.y + a1.z + a1.w;
  float ss = a0.x * a0.x + a0.y * a0.y + a0.z * a0.z + a0.w * a0.w +
             a1.x * a1.x + a1.y * a1.y + a1.z * a1.z + a1.w * a1.w;
  #pragma unroll
  for (int m = 1; m < 64; m <<= 1) { s += __shfl_xor(s, m, 64); ss += __shfl_xor(ss, m, 64); }
  const float mean = s * (1.f / D_);
  const float rs = rsqrtf(ss * (1.f / D_) - mean * mean + 1e-5f);
  const float4 g0 = *(const float4*)(g + lane * 8);
  const float4 g1 = *(const float4*)(g + lane * 8 + 4);
  const float4 b0 = *(const float4*)(bta + lane * 8);
  const float4 b1 = *(const float4*)(bta + lane * 8 + 4);
  bf8_t res;
  res[0] = (short)f2bf((a0.x - mean) * rs * g0.x + b0.x);
  res[1] = (short)f2bf((a0.y - mean) * rs * g0.y + b0.y);
  res[2] = (short)f2bf((a0.z - mean) * rs * g0.z + b0.z);
  res[3] = (short)f2bf((a0.w - mean) * rs * g0.w + b0.w);
  res[4] = (short)f2bf((a1.x - mean) * rs * g1.x + b1.x);
  res[5] = (short)f2bf((a1.y - mean) * rs * g1.y + b1.y);
  res[6] = (short)f2bf((a1.z - mean) * rs * g1.z + b1.z);
  res[7] = (short)f2bf((a1.w - mean) * rs * g1.w + b1.w);
  *(bf8_t*)(outp + lane * 8) = res;
}

// ---------------- prep: cvt + ln1 + scatter + edge_gemm(inline geo-LN), one launch --------
// block ranges: [0,1536) cvt (8 f32/thread); [1536,2560) LN(x) 8 rows/block;
//               [2560,2688) scatter; [2688,3200) edge-bias GEMM (padded LDS rows).
#define WEBP 264
#define WGEOP 72
__global__ __launch_bounds__(256) void prep_kernel(
    // cvt
    const float* __restrict__ wq, const float* __restrict__ wk,
    const float* __restrict__ wv, const float* __restrict__ wo,
    const float* __restrict__ w1, const float* __restrict__ w2,
    u16* __restrict__ dq, u16* __restrict__ dk, u16* __restrict__ dv,
    u16* __restrict__ dox, u16* __restrict__ d1, u16* __restrict__ d2,
    // ln1
    const float* __restrict__ x, const float* __restrict__ ng,
    const float* __restrict__ nb, u16* __restrict__ xn,
    // scatter
    const int* __restrict__ edges, const float* __restrict__ rmask,
    int* __restrict__ win,
    // edge
    const float* __restrict__ remb, const float* __restrict__ rgeo,
    const float* __restrict__ Web, const float* __restrict__ beb,
    const float* __restrict__ glng, const float* __restrict__ glnb,
    const float* __restrict__ Wgeo, const float* __restrict__ bgeo,
    float* __restrict__ tb) {
  __shared__ u16 sWeb[16 * WEBP];
  __shared__ u16 sWgeo[16 * WGEOP];
  __shared__ float sLgb[128];
  const int t = threadIdx.x;
  const int blk0 = blockIdx.x;

  if (blk0 < 1536) {
    // ---- weight f32 -> bf16: 8 floats/thread (2x float4 -> one 16B store) ----
    int blk = blk0;
    const float* src; u16* dst;
    if (blk < 128)        { src = wq; dst = dq; }
    else if (blk < 256)   { src = wk; dst = dk; blk -= 128; }
    else if (blk < 384)   { src = wv; dst = dv; blk -= 256; }
    else if (blk < 512)   { src = wo; dst = dox; blk -= 384; }
    else if (blk < 1024)  { src = w1; dst = d1; blk -= 512; }
    else                  { src = w2; dst = d2; blk -= 1024; }
    const int i = (blk * 256 + t) * 8;
    const float4 v0 = *(const float4*)(src + i);
    const float4 v1 = *(const float4*)(src + i + 4);
    bf8_t o;
    o[0] = (short)f2bf(v0.x); o[1] = (short)f2bf(v0.y);
    o[2] = (short)f2bf(v0.z); o[3] = (short)f2bf(v0.w);
    o[4] = (short)f2bf(v1.x); o[5] = (short)f2bf(v1.y);
    o[6] = (short)f2bf(v1.z); o[7] = (short)f2bf(v1.w);
    *(bf8_t*)(dst + i) = o;
  } else if (blk0 < 2560) {
    // ---- LN(x): 8 rows per block, one wave per row x2 ----
    const int base = (blk0 - 1536) * 8 + (t >> 6) * 2;
    const int lane = t & 63;
    #pragma unroll
    for (int r = 0; r < 2; ++r) {
      const int row = base + r;
      ln_row_wave(x + (size_t)row * D_, lane, ng, nb, xn + (size_t)row * D_);
    }
  } else if (blk0 < 2688) {
    // ---- winner scatter (np last-write-wins) ----
    const int idx = (blk0 - 2560) * 256 + t;  // b*E + e
    if (rmask[idx] != 0.f) {
      const int b = idx >> 10, e = idx & (E_ - 1);
      int s = edges[2 * idx], d = edges[2 * idx + 1];
      s = min(max(s, 0), N_ - 1);
      d = min(max(d, 0), N_ - 1);
      int* wb = win + (size_t)b * N_ * N_;
      atomicMax(&wb[s * N_ + d], e);        // pass 1: priority e
      atomicMax(&wb[d * N_ + s], E_ + e);   // pass 2: priority E+e
    }
  } else {
    // ---- edge bias GEMM with inline geo LN ----
    const int eblk = blk0 - 2688;
    for (int i = t; i < 2048; i += 256) {
      const int r = i >> 8, c = i & 255;
      sWeb[r * WEBP + c] = f2bf(Web[i]);
      sWeb[(8 + r) * WEBP + c] = 0;
    }
    for (int i = t; i < 512; i += 256) {
      const int r = i >> 6, c = i & 63;
      sWgeo[r * WGEOP + c] = f2bf(Wgeo[i]);
      sWgeo[(8 + r) * WGEOP + c] = 0;
    }
    if (t < 64) { sLgb[t] = glng[t]; sLgb[64 + t] = glnb[t]; }
    __syncthreads();
    const int wave = t >> 6, lane = t & 63;
    const int am = lane & 15, quad = lane >> 4;
    const int e0 = eblk * 64 + wave * 16;

    f4_t acc = f4_t{0.f, 0.f, 0.f, 0.f};
    const float* ar = remb + (size_t)(e0 + am) * 256 + quad * 8;
    #pragma unroll
    for (int kt = 0; kt < 256; kt += 32) {
      const float4 p0 = *(const float4*)(ar + kt);
      const float4 p1 = *(const float4*)(ar + kt + 4);
      bf8_t a;
      a[0] = (short)f2bf(p0.x); a[1] = (short)f2bf(p0.y);
      a[2] = (short)f2bf(p0.z); a[3] = (short)f2bf(p0.w);
      a[4] = (short)f2bf(p1.x); a[5] = (short)f2bf(p1.y);
      a[6] = (short)f2bf(p1.z); a[7] = (short)f2bf(p1.w);
      const bf8_t bv = *(const bf8_t*)&sWeb[am * WEBP + kt + quad * 8];
      acc = mfma16(a, bv, acc);
    }
    // geo: row (e0+am), lane holds elems quad*8..+7 and 32+quad*8..+7
    const float* gr = rgeo + (size_t)(e0 + am) * 64;
    float v[16];
    {
      const float4 p0 = *(const float4*)(gr + quad * 8);
      const float4 p1 = *(const float4*)(gr + quad * 8 + 4);
      const float4 p2 = *(const float4*)(gr + 32 + quad * 8);
      const float4 p3 = *(const float4*)(gr + 32 + quad * 8 + 4);
      v[0] = p0.x; v[1] = p0.y; v[2] = p0.z; v[3] = p0.w;
      v[4] = p1.x; v[5] = p1.y; v[6] = p1.z; v[7] = p1.w;
      v[8] = p2.x; v[9] = p2.y; v[10] = p2.z; v[11] = p2.w;
      v[12] = p3.x; v[13] = p3.y; v[14] = p3.z; v[15] = p3.w;
    }
    float s = 0.f, ss = 0.f;
    #pragma unroll
    for (int j = 0; j < 16; ++j) { s += v[j]; ss += v[j] * v[j]; }
    s += __shfl_xor(s, 16, 64);  ss += __shfl_xor(ss, 16, 64);
    s += __shfl_xor(s, 32, 64);  ss += __shfl_xor(ss, 32, 64);
    const float mean = s * (1.f / 64.f);
    const float rs = rsqrtf(ss * (1.f / 64.f) - mean * mean + 1e-5f);
    bf8_t a2, a3;
    #pragma unroll
    for (int j = 0; j < 8; ++j) {
      a2[j] = (short)f2bf((v[j] - mean) * rs * sLgb[quad * 8 + j] + sLgb[64 + quad * 8 + j]);
      a3[j] = (short)f2bf((v[8 + j] - mean) * rs * sLgb[32 + quad * 8 + j] +
                          sLgb[96 + quad * 8 + j]);
    }
    acc = mfma16(a2, *(const bf8_t*)&sWgeo[am * WGEOP + quad * 8], acc);
    acc = mfma16(a3, *(const bf8_t*)&sWgeo[am * WGEOP + 32 + quad * 8], acc);
    if (am < 8) {
      const float bias_v = beb[am] + bgeo[am];
      #pragma unroll
      for (int r = 0; r < 4; ++r) {
        const int eg = e0 + quad * 4 + r;
        tb[(size_t)((eg >> 10) * H_ + am) * E_ + (eg & (E_ - 1))] = acc[r] + bias_v;
      }
    }
  }
}

// ---------------- LayerNorm: 8 rows/block, wave per row x2 (f32 in -> bf16 out) --------
__global__ __launch_bounds__(256) void ln_kernel(const float* __restrict__ x,
                                                 const float* __restrict__ g,
                                                 const float* __restrict__ bta,
                                                 u16* __restrict__ out) {
  const int base = blockIdx.x * 8 + (threadIdx.x >> 6) * 2;
  const int lane = threadIdx.x & 63;
  #pragma unroll
  for (int r = 0; r < 2; ++r) {
    const int row = base + r;
    ln_row_wave(x + (size_t)row * D_, lane, g, bta, out + (size_t)row * D_);
  }
}

// ---------------- sparse attention: one wave per (b,row), all heads ----------------
__global__ __launch_bounds__(256) void attn_kernel(
    const u16* __restrict__ q, const u16* __restrict__ k, const u16* __restrict__ v,
    const float* __restrict__ tb, const int* __restrict__ win,
    const float* __restrict__ nm, u16* __restrict__ out) {
  const int t = threadIdx.x;
  const int wave = t >> 6, lane = t & 63;
  const int g = blockIdx.x * 4 + wave;      // b*N + row
  const int b = g >> 8, row = g & (N_ - 1);
  u16* op = out + (size_t)g * D_ + lane * 8;
  const float nmr = nm[g];
  if (nmr == 0.f) {
    bf8_t z = 0;
    *(bf8_t*)op = z;
    return;
  }
  float qf[8];
  {
    const bf8_t qv = *(const bf8_t*)(q + (size_t)g * D_ + lane * 8);
    #pragma unroll
    for (int j = 0; j < 8; ++j) qf[j] = bf2f((u16)qv[j]);
  }
  int4 w4 = *(const int4*)(win + (size_t)g * N_ + lane * 4);
  if (lane == (row >> 2)) {
    const int sl = row & 3;
    if (sl == 0)      { if (w4.x == -1) w4.x = 0x7FFFFFFF; }
    else if (sl == 1) { if (w4.y == -1) w4.y = 0x7FFFFFFF; }
    else if (sl == 2) { if (w4.z == -1) w4.z = 0x7FFFFFFF; }
    else              { if (w4.w == -1) w4.w = 0x7FFFFFFF; }
  }
  const float* tbh = tb + (size_t)(b * H_ + (lane >> 3)) * E_;
  const float* nmb = nm + b * N_;
  const u16* kb = k + (size_t)b * N_ * D_;
  const u16* vb = v + (size_t)b * N_ * D_;
  float m = -3.402823466e38f, sum = 0.f;
  float o[8];
  #pragma unroll
  for (int j = 0; j < 8; ++j) o[j] = 0.f;
  #pragma unroll
  for (int c = 0; c < 4; ++c) {
    const int wc = (c == 0) ? w4.x : (c == 1) ? w4.y : (c == 2) ? w4.z : w4.w;
    unsigned long long mk = __ballot(wc != -1);
    while (mk) {
      const int jl = __builtin_ctzll(mk);
      mk &= mk - 1;
      const int col = jl * 4 + c;
      const int wv = __shfl(wc, jl, 64);
      const float nmc = nmb[col];
      if (nmc == 0.f) continue;
      const bf8_t kv = *(const bf8_t*)(kb + (size_t)col * D_ + lane * 8);
      float d = 0.f;
      #pragma unroll
      for (int j = 0; j < 8; ++j) d += qf[j] * bf2f((u16)kv[j]);
      d += __shfl_xor(d, 1, 64);
      d += __shfl_xor(d, 2, 64);
      d += __shfl_xor(d, 4, 64);
      float s = d * 0.125f;
      if ((unsigned)wv < 2048u) s += tbh[wv & (E_ - 1)];
      const bf8_t vv = *(const bf8_t*)(vb + (size_t)col * D_ + lane * 8);
      if (s > m) {
        const float sc = __expf(m - s);
        sum *= sc;
        #pragma unroll
        for (int j = 0; j < 8; ++j) o[j] *= sc;
        m = s;
      }
      const float p = __expf(s - m);
      sum += p;
      #pragma unroll
      for (int j = 0; j < 8; ++j) o[j] += p * bf2f((u16)vv[j]);
    }
  }
  const float rinv = 1.f / sum;
  bf8_t res;
  #pragma unroll
  for (int j = 0; j < 8; ++j) res[j] = (short)f2bf(o[j] * rinv);
  *(bf8_t*)op = res;
}

// ---------------- GEMM: C = A @ W^T (+epilogue), global_load_lds staging ----------------
// Round-12 verified config (best measured, 285.4us): BM=128 single-buffer, swapped MFMA
// (D rows<-N, cols<-M) -> vector ushort4/float4 epilogue. SIX structural variants
// (BN 256, dbuf-drain, counted vmcnt@128, BM=64, BK=128, 3-deep@64^2) all landed
// 288-327: shape-imposed basin. Do not perturb.
template <int MODE, int BN>
__global__ __launch_bounds__(256, 2) void gemm_k(
    const u16* __restrict__ A,
    const u16* __restrict__ W0, const u16* __restrict__ W1, const u16* __restrict__ W2,
    const float* __restrict__ b0, const float* __restrict__ b1, const float* __restrict__ b2,
    void* d0, void* d1, void* d2,
    const void* res, const float* __restrict__ nmask, int K) {
  constexpr int MJ = BN / 32;
  constexpr int CB = BN / 32;
  __shared__ u16 As[128 * 64];
  __shared__ u16 Bs[BN * 64];
  const int tid = threadIdx.x;
  const int wave = tid >> 6, lane = tid & 63;
  const int am = lane & 15, quad = lane >> 4;
  const int m0 = blockIdx.x * 128;
  int n0, proj = 0;
  const u16* W;
  const float* bias;
  if constexpr (MODE == 0) {
    constexpr int NPB = 512 / BN;  // n-blocks per projection
    proj = blockIdx.y / NPB;
    n0 = (blockIdx.y % NPB) * BN;
    W = proj == 0 ? W0 : (proj == 1 ? W1 : W2);
    bias = proj == 0 ? b0 : (proj == 1 ? b1 : b2);
  } else {
    n0 = blockIdx.y * BN;
    W = W0;
    bias = b0;
  }
  const int wm = (wave >> 1) * 64;
  const int wn = (wave & 1) * (BN / 2);

  f4_t acc[4][MJ];
  #pragma unroll
  for (int i = 0; i < 4; ++i)
    #pragma unroll
    for (int j = 0; j < MJ; ++j) acc[i][j] = f4_t{0.f, 0.f, 0.f, 0.f};

  int arow[4], aq[4], brow[CB], bq[CB];
  #pragma unroll
  for (int c = 0; c < 4; ++c) {
    const int g = (wave * 4 + c) * 64 + lane;
    arow[c] = g >> 3;
    aq[c] = (g & 7) ^ (arow[c] & 7);
  }
  #pragma unroll
  for (int c = 0; c < CB; ++c) {
    const int g = (wave * CB + c) * 64 + lane;
    brow[c] = g >> 3;
    bq[c] = (g & 7) ^ (brow[c] & 7);
  }

  for (int kt = 0; kt < K; kt += 64) {
    #pragma unroll
    for (int c = 0; c < 4; ++c)
      gload_lds16(A + (size_t)(m0 + arow[c]) * K + kt + aq[c] * 8, &As[(wave * 4 + c) * 512]);
    #pragma unroll
    for (int c = 0; c < CB; ++c)
      gload_lds16(W + (size_t)(n0 + brow[c]) * K + kt + bq[c] * 8, &Bs[(wave * CB + c) * 512]);
    __syncthreads();
    #pragma unroll
    for (int kc = 0; kc < 2; ++kc) {
      bf8_t af[4], bfv[MJ];
      #pragma unroll
      for (int i = 0; i < 4; ++i) {
        const int r = wm + i * 16 + am;
        af[i] = *(const bf8_t*)&As[r * 64 + (((kc * 4 + quad) ^ (r & 7)) * 8)];
      }
      #pragma unroll
      for (int j = 0; j < MJ; ++j) {
        const int r = wn + j * 16 + am;
        bfv[j] = *(const bf8_t*)&Bs[r * 64 + (((kc * 4 + quad) ^ (r & 7)) * 8)];
      }
      #pragma unroll
      for (int i = 0; i < 4; ++i)
        #pragma unroll
        for (int j = 0; j < MJ; ++j)
          acc[i][j] = mfma16(bfv[j], af[i], acc[i][j]);  // swapped: D rows<-N, cols<-M
    }
    __syncthreads();
  }

  // Epilogue: lane holds rows (wm+i*16+am), cols (wn+j*16+quad*4 .. +3) -> vector stores
  const int row0 = m0 + wm + am;
  const int col0 = n0 + wn + quad * 4;
  #pragma unroll
  for (int j = 0; j < MJ; ++j) {
    const int col = col0 + j * 16;
    const float4 bv4 = *(const float4*)(bias + col);
    #pragma unroll
    for (int i = 0; i < 4; ++i) {
      const int row = row0 + i * 16;
      float v0 = acc[i][j][0] + bv4.x;
      float v1 = acc[i][j][1] + bv4.y;
      float v2 = acc[i][j][2] + bv4.z;
      float v3 = acc[i][j][3] + bv4.w;
      if constexpr (MODE == 0) {
        u16* dst = (u16*)(proj == 0 ? d0 : (proj == 1 ? d1 : d2));
        ushort4 o; o.x = f2bf(v0); o.y = f2bf(v1); o.z = f2bf(v2); o.w = f2bf(v3);
        *(ushort4*)(dst + (size_t)row * D_ + col) = o;
      } else if constexpr (MODE == 2) {
        const float4 rr = *(const float4*)((const float*)res + (size_t)row * D_ + col);
        float4 o; o.x = v0 + rr.x; o.y = v1 + rr.y; o.z = v2 + rr.z; o.w = v3 + rr.w;
        *(float4*)((float*)d0 + (size_t)row * D_ + col) = o;
      } else if constexpr (MODE == 3) {
        v0 = v0 / (1.f + __expf(-v0));
        v1 = v1 / (1.f + __expf(-v1));
        v2 = v2 / (1.f + __expf(-v2));
        v3 = v3 / (1.f + __expf(-v3));
        ushort4 o; o.x = f2bf(v0); o.y = f2bf(v1); o.z = f2bf(v2); o.w = f2bf(v3);
        *(ushort4*)((u16*)d0 + (size_t)row * 2048 + col) = o;
      } else {
        const float4 rr = *(const float4*)((const float*)res + (size_t)row * D_ + col);
        const float nmv = nmask[row];
        float4 o;
        o.x = (v0 + rr.x) * nmv; o.y = (v1 + rr.y) * nmv;
        o.z = (v2 + rr.z) * nmv; o.w = (v3 + rr.w) * nmv;
        *(float4*)((float*)d0 + (size_t)row * D_ + col) = o;
      }
    }
  }
}

extern "C" void kernel_launch(void* const* d_in, const int* in_sizes, int n_in,
                              void* d_out, int out_size, void* d_ws, size_t ws_size,
                              hipStream_t stream) {
  const float* x     = (const float*)d_in[0];
  const float* nm    = (const float*)d_in[1];
  const int*   edges = (const int*)d_in[2];
  const float* rmask = (const float*)d_in[3];
  const float* remb  = (const float*)d_in[4];
  const float* rgeo  = (const float*)d_in[5];
  const float* Wq = (const float*)d_in[6];  const float* bq = (const float*)d_in[7];
  const float* Wk = (const float*)d_in[8];  const float* bk = (const float*)d_in[9];
  const float* Wv = (const float*)d_in[10]; const float* bv = (const float*)d_in[11];
  const float* Web = (const float*)d_in[12]; const float* beb = (const float*)d_in[13];
  const float* glng = (const float*)d_in[14]; const float* glnb = (const float*)d_in[15];
  const float* Wgeo = (const float*)d_in[16]; const float* bgeo = (const float*)d_in[17];
  const float* Wout = (const float*)d_in[18]; const float* bout = (const float*)d_in[19];
  const float* ng = (const float*)d_in[20]; const float* nb = (const float*)d_in[21];
  const float* fg = (const float*)d_in[22]; const float* fb = (const float*)d_in[23];
  const float* Wff1 = (const float*)d_in[24]; const float* bff1 = (const float*)d_in[25];
  const float* Wff2 = (const float*)d_in[26]; const float* bff2 = (const float*)d_in[27];

  char* ws = (char*)d_ws;
  u16*   xn      = (u16*)(ws + 0);
  u16*   qb      = (u16*)(ws + 8388608);
  u16*   kb      = (u16*)(ws + 16777216);
  u16*   vb      = (u16*)(ws + 25165824);
  u16*   h1      = (u16*)(ws + 0);          // overlays dead xn/qb/kb/vb in FF
  int*   win     = (int*)(ws + 33554432);
  u16*   x2n     = (u16*)(ws + 33554432);   // overlays dead win
  float* tb      = (float*)(ws + 41943040);
  u16* Wq16   = (u16*)(ws + 42991616);
  u16* Wk16   = (u16*)(ws + 43515904);
  u16* Wv16   = (u16*)(ws + 44040192);
  u16* Wout16 = (u16*)(ws + 44564480);
  u16* Wff116 = (u16*)(ws + 45088768);
  u16* Wff216 = (u16*)(ws + 47185920);
  u16*   attnout = xn;
  float* out     = (float*)d_out;

  // 0. win init, then fused prep (cvt + ln1 + scatter + edge-bias GEMM) in ONE launch
  hipMemsetAsync(win, 0xFF, (size_t)B_ * N_ * N_ * sizeof(int), stream);
  prep_kernel<<<3200, 256, 0, stream>>>(
      Wq, Wk, Wv, Wout, Wff1, Wff2, Wq16, Wk16, Wv16, Wout16, Wff116, Wff216,
      x, ng, nb, xn,
      edges, rmask, win,
      remb, rgeo, Web, beb, glng, glnb, Wgeo, bgeo, tb);
  // 1. fused QKV projections, all plain (B*N, D) bf16; BN=128 -> grid.y = 3 proj * 4
  gemm_k<0, 128><<<dim3(64, 12), 256, 0, stream>>>(xn, Wq16, Wk16, Wv16, bq, bk, bv,
                                                   (void*)qb, (void*)kb, (void*)vb,
                                                   nullptr, nullptr, D_);
  // 2. sparse attention -> attnout (bf16); one wave per (b,row)
  attn_kernel<<<dim3(B_ * N_ / 4), 256, 0, stream>>>(qb, kb, vb, tb, win, nm, attnout);
  // 3. x2 = x + attnout @ Wout^T + bout  -> d_out (f32); BN=64
  gemm_k<2, 64><<<dim3(64, 8), 256, 0, stream>>>(attnout, Wout16, nullptr, nullptr,
                                                 bout, nullptr, nullptr,
                                                 (void*)out, nullptr, nullptr,
                                                 (const void*)x, nullptr, D_);
  // 4. x2n = LN(x2); 8 rows/block wave-per-row
  ln_kernel<<<B_ * N_ / 8, 256, 0, stream>>>(out, fg, fb, x2n);
  // 5. h1 = silu(x2n @ Wff1^T + bff1); BN=128
  gemm_k<3, 128><<<dim3(64, 16), 256, 0, stream>>>(x2n, Wff116, nullptr, nullptr,
                                                   bff1, nullptr, nullptr,
                                                   (void*)h1, nullptr, nullptr, nullptr, nullptr, D_);
  // 6. out = (x2 + h1 @ Wff2^T + bff2) * node_mask; BN=64
  gemm_k<4, 64><<<dim3(64, 8), 256, 0, stream>>>(h1, Wff216, nullptr, nullptr,
                                                 bff2, nullptr, nullptr,
                                                 (void*)out, nullptr, nullptr,
                                                 (const void*)out, nm, 2048);
}